// Round 27
// baseline (104.492 us; speedup 1.0000x reference)
//
#include <hip/hip_runtime.h>

typedef __attribute__((ext_vector_type(8))) short short8;
typedef __attribute__((ext_vector_type(4))) short short4v;
typedef __attribute__((ext_vector_type(4))) float f32x4;
typedef unsigned short ushort_t;

#define MFMA_BF16_K32(A,B,C) __builtin_amdgcn_mfma_f32_16x16x32_bf16(A,B,C,0,0,0)
#define MFMA_BF16_K16(A,B,C) __builtin_amdgcn_mfma_f32_16x16x16bf16_1k(A,B,C,0,0,0)

static constexpr int Bc  = 4;
static constexpr int Nn  = 8000;
static constexpr int N2  = 8192;
static constexpr int DIMc = 256;
static constexpr float SC2 = 0.36067376022224085f;   // 0.25 * log2(e), folded into Wq

__device__ __forceinline__ unsigned short f2bf(float f){
  unsigned int u = __float_as_uint(f);
  u = (u + 0x7FFFu + ((u >> 16) & 1u)) >> 16;
  return (unsigned short)u;
}
__device__ __forceinline__ uint2 pack4(f32x4 v){
  uint2 r;
  r.x = (unsigned)f2bf(v[0]) | ((unsigned)f2bf(v[1]) << 16);
  r.y = (unsigned)f2bf(v[2]) | ((unsigned)f2bf(v[3]) << 16);
  return r;
}
__device__ __forceinline__ unsigned cvtpk(float lo, float hi){
  unsigned r;
  asm("v_cvt_pk_bf16_f32 %0, %1, %2" : "=v"(r) : "v"(lo), "v"(hi));
  return r;
}
// raw v_exp_f32: args bounded (|x| < 40), no denorm fixup needed
__device__ __forceinline__ float rexp2(float x){
  float r;
  asm("v_exp_f32 %0, %1" : "=v"(r) : "v"(x));
  return r;
}
// permuted position of token t within its 32-block (V layout for dense PV loads)
__device__ __forceinline__ int vperm(int t){
  return (t & ~31) | (((t >> 2) & 3) * 8 + ((t >> 4) & 1) * 4 + (t & 3));
}

// ---- prep: Wcs/Wps fragment-major weights, vgT (token-permuted), kgb ----
__global__ __launch_bounds__(256) void prep_kernel(
    const float* __restrict__ Wq, const float* __restrict__ Wk,
    const float* __restrict__ Wv, const float* __restrict__ Wp,
    const float* __restrict__ kg, const float* __restrict__ vg,
    ushort_t* __restrict__ Wcs, ushort_t* __restrict__ Wps,
    ushort_t* __restrict__ vgT, ushort_t* __restrict__ kgb)
{
  int i = blockIdx.x * 256 + threadIdx.x;          // 294912 total
  if (i < 131072){
    int jj = i & 7, f = i >> 3;
    int l = f & 63, kc = (f >> 6) & 7, ctw = f >> 9;       // ctw 0..31
    int col = ctw * 16 + (l & 15);                          // 0..511
    int k   = kc * 32 + (l >> 4) * 8 + jj;
    float v;
    if (col < 128)      v = Wq[col * 256 + k] * SC2;
    else if (col < 256) v = Wk[(col - 128) * 256 + k];
    else                v = Wv[(col - 256) * 256 + k];
    Wcs[i] = f2bf(v);
  } else if (i < 196608){
    int o = i - 131072;                            // Wps, ctw 0..15
    int jj = o & 7, f = o >> 3;
    int l = f & 63, kc = (f >> 6) & 7, ctw = f >> 9;
    int col = ctw * 16 + (l & 15);
    int k   = kc * 32 + (l >> 4) * 8 + jj;
    Wps[o] = f2bf(Wp[col * 256 + k]);
  } else if (i < 262144){
    int o = i - 196608;                            // vg [8,256,32] -> vgT permuted
    int c = o & 31, m = (o >> 5) & 255, h = o >> 13;
    vgT[(h * 32 + c) * 256 + vperm(m)] = f2bf(vg[o]);
  } else {
    int j = i - 262144;
    kgb[j] = f2bf(kg[j]);
  }
}

// ---- QKV projection, M=32 per block (retest: 1000 blocks now that weight
// loads are fragment-major/L2-resident; R17's regression cause is gone) ----
__global__ __launch_bounds__(256) void proj_kernel(
    const float* __restrict__ X, const ushort_t* __restrict__ Wcs,
    const int* __restrict__ idx, ushort_t* __restrict__ qh,
    ushort_t* __restrict__ kh, ushort_t* __restrict__ vT)
{
  const int b  = blockIdx.y;
  const int r0 = blockIdx.x * 32;
  const int tid = threadIdx.x;
  const int w = tid >> 6, l = tid & 63, g4 = l >> 4, q16 = l & 15;
  __shared__ unsigned Xs[32][132];   // bf16x2 rows, pitch 132, 16.9 KB

  #pragma unroll
  for (int r = 0; r < 8; ++r){
    int row = r * 4 + w;
    int tok = idx[b * Nn + r0 + row];
    float4 xv = reinterpret_cast<const float4*>(X + (size_t)(b * Nn + tok) * DIMc)[l];
    uint2 u; u.x = cvtpk(xv.x, xv.y); u.y = cvtpk(xv.z, xv.w);
    *reinterpret_cast<uint2*>(&Xs[row][l * 2]) = u;
  }
  __syncthreads();

  f32x4 acc[2][8];
  #pragma unroll
  for (int mt = 0; mt < 2; ++mt)
    #pragma unroll
    for (int ct = 0; ct < 8; ++ct) acc[mt][ct] = f32x4{0.f, 0.f, 0.f, 0.f};
  #pragma unroll
  for (int kc = 0; kc < 8; ++kc){
    short8 a[2];
    #pragma unroll
    for (int mt = 0; mt < 2; ++mt){
      uint4 au = *reinterpret_cast<const uint4*>(&Xs[mt * 16 + q16][kc * 16 + g4 * 4]);
      a[mt] = __builtin_bit_cast(short8, au);
    }
    #pragma unroll
    for (int ct = 0; ct < 8; ++ct){
      short8 bb = *reinterpret_cast<const short8*>(
          Wcs + ((size_t)((w * 8 + ct) * 8 + kc) * 64 + l) * 8);   // coalesced 1KB
      #pragma unroll
      for (int mt = 0; mt < 2; ++mt) acc[mt][ct] = MFMA_BF16_K32(a[mt], bb, acc[mt][ct]);
    }
  }
  if (w < 2){
    ushort_t* dst = (w == 0) ? qh : kh;
    #pragma unroll
    for (int ct = 0; ct < 8; ++ct){
      #pragma unroll
      for (int mt = 0; mt < 2; ++mt){
        #pragma unroll
        for (int r = 0; r < 4; ++r){
          int j = r0 + mt * 16 + g4 * 4 + r;
          dst[((size_t)(b * 8 + ct) * N2 + j) * 16 + q16] = f2bf(acc[mt][ct][r]);
        }
      }
    }
  } else {
    #pragma unroll
    for (int ct = 0; ct < 8; ++ct){
      int col = (w - 2) * 128 + ct * 16 + q16;
      #pragma unroll
      for (int mt = 0; mt < 2; ++mt){
        int jb = r0 + g4 * 8 + mt * 4;   // vperm of rows r0+mt*16+g4*4+r, r consecutive
        *reinterpret_cast<uint2*>(vT + (size_t)(b * 256 + col) * N2 + jb) = pack4(acc[mt][ct]);
      }
    }
  }
}

// ---- reflected tails ----
__global__ __launch_bounds__(256) void reflect_fill_kernel(
    ushort_t* __restrict__ qh, ushort_t* __restrict__ kh, ushort_t* __restrict__ vT)
{
  int t = blockIdx.x * 256 + threadIdx.x;
  if (t < 24576){
    int e = t & 1;
    int r = (t >> 1) % 192;
    int p = (t >> 1) / 192;
    int b = p >> 4, q = p & 15;
    ushort_t* base = (q < 8) ? qh : kh;
    int h = q & 7;
    size_t plane = (size_t)(b * 8 + h) * N2 * 16;
    const uint4* src = reinterpret_cast<const uint4*>(base + plane + (size_t)(7999 - r) * 16);
    uint4*       dst = reinterpret_cast<uint4*>(base + plane + (size_t)(8000 + r) * 16);
    dst[e] = src[e];
  } else {
    int u = t - 24576;
    int r = u / 192, i2 = u % 192;
    vT[(size_t)r * N2 + vperm(8000 + i2)] = vT[(size_t)r * N2 + vperm(7999 - i2)];
  }
}

// ---- fused attention: wave = (head, pass), fully independent (no LDS/barrier).
// grid (63, 4, 4); 4 waves = 2 heads x {local, global}; partial buffers
// summed inside final's K=512 GEMM. ----
__global__ __launch_bounds__(256) void attn_kernel(
    const ushort_t* __restrict__ qh, const ushort_t* __restrict__ kh,
    const ushort_t* __restrict__ vT,
    const ushort_t* __restrict__ kg, const ushort_t* __restrict__ vgT,
    ushort_t* __restrict__ aoh0, ushort_t* __restrict__ aoh1)
{
  const int go = blockIdx.x, hp = blockIdx.y, b = blockIdx.z;
  const int tid = threadIdx.x;
  const int w = tid >> 6, l = tid & 63, g4 = l >> 4, q16 = l & 15;
  const int h = hp * 2 + (w >> 1);
  const int pass = w & 1;                    // 0 = local window, 1 = global
  const f32x4 z4 = {0.f, 0.f, 0.f, 0.f};
  const size_t bh = (size_t)(b * 8 + h);
  const ushort_t* Qb = qh + (bh * N2 + go * 128) * 16;
  ushort_t*       Ob = (pass ? aoh1 : aoh0) + (bh * N2 + go * 128) * 32;

  short8 ones;
  #pragma unroll
  for (int j = 0; j < 8; ++j) ones[j] = (short)0x3F80;   // bf16 1.0

  const ushort_t* kbase = pass ? (kg + (size_t)h * 256 * 16)
                               : (kh + (bh * N2 + go * 128) * 16);
  short4v karr[16];
  #pragma unroll
  for (int t = 0; t < 16; ++t)
    karr[t] = *reinterpret_cast<const short4v*>(
        kbase + (size_t)(t * 16 + q16) * 16 + g4 * 4);
  const ushort_t* v0;
  size_t rstride;
  if (!pass){
    v0 = vT + (size_t)(b * 256 + h * 32) * N2 + go * 128 + (size_t)q16 * N2 + g4 * 8;
    rstride = (size_t)16 * N2;
  } else {
    v0 = vgT + (size_t)h * 32 * 256 + (size_t)q16 * 256 + g4 * 8;
    rstride = (size_t)16 * 256;
  }
  uint4 va[8], vb[8];
  #pragma unroll
  for (int t2 = 0; t2 < 8; ++t2){
    va[t2] = *reinterpret_cast<const uint4*>(v0 + t2 * 32);
    vb[t2] = *reinterpret_cast<const uint4*>(v0 + rstride + t2 * 32);
  }

  #pragma unroll 2
  for (int qt = 0; qt < 8; ++qt){
    short4v qf = *reinterpret_cast<const short4v*>(
        Qb + (size_t)(qt * 16 + q16) * 16 + g4 * 4);
    // ---- S^T = K @ Q^T (scale pre-folded into q) ----
    f32x4 s[16];
    __builtin_amdgcn_s_setprio(1);
    #pragma unroll
    for (int t = 0; t < 16; ++t) s[t] = MFMA_BF16_K16(karr[t], qf, z4);
    __builtin_amdgcn_s_setprio(0);
    // ---- P = exp2(S) packed bf16 ----
    uint4 p4[8];
    #pragma unroll
    for (int t2 = 0; t2 < 8; ++t2){
      float e0 = rexp2(s[2*t2][0]);
      float e1 = rexp2(s[2*t2][1]);
      float e2 = rexp2(s[2*t2][2]);
      float e3 = rexp2(s[2*t2][3]);
      float f0 = rexp2(s[2*t2+1][0]);
      float f1 = rexp2(s[2*t2+1][1]);
      float f2 = rexp2(s[2*t2+1][2]);
      float f3 = rexp2(s[2*t2+1][3]);
      p4[t2].x = cvtpk(e0, e1); p4[t2].y = cvtpk(e2, e3);
      p4[t2].z = cvtpk(f0, f1); p4[t2].w = cvtpk(f2, f3);
    }
    // ---- O^T = V^T @ P ; denominator via ones-MFMA (no shfl) ----
    f32x4 o0 = z4, o1 = z4, dacc = z4;
    __builtin_amdgcn_s_setprio(1);
    #pragma unroll
    for (int t2 = 0; t2 < 8; ++t2){
      short8 pf = __builtin_bit_cast(short8, p4[t2]);
      o0   = MFMA_BF16_K32(__builtin_bit_cast(short8, va[t2]), pf, o0);
      o1   = MFMA_BF16_K32(__builtin_bit_cast(short8, vb[t2]), pf, o1);
      dacc = MFMA_BF16_K32(ones, pf, dacc);
    }
    __builtin_amdgcn_s_setprio(0);
    float invd = 1.0f / dacc[0];
    uint2 s0, s1;
    s0.x = cvtpk(o0[0] * invd, o0[1] * invd);
    s0.y = cvtpk(o0[2] * invd, o0[3] * invd);
    s1.x = cvtpk(o1[0] * invd, o1[1] * invd);
    s1.y = cvtpk(o1[2] * invd, o1[3] * invd);
    size_t base = (size_t)(qt * 16 + q16) * 32;
    *reinterpret_cast<uint2*>(Ob + base + g4 * 4)      = s0;
    *reinterpret_cast<uint2*>(Ob + base + 16 + g4 * 4) = s1;
  }
}

// ---- final: out[idx[b,j]] = (A0[b,j] + A1[b,j]) @ Wp^T via K=512 GEMM ----
__global__ __launch_bounds__(256) void final_kernel(
    const ushort_t* __restrict__ A0, const ushort_t* __restrict__ A1,
    const ushort_t* __restrict__ Wps,
    const int* __restrict__ idx, float* __restrict__ out)
{
  const int b  = blockIdx.y;
  const int r0 = blockIdx.x * 64;
  const int tid = threadIdx.x;
  const int w = tid >> 6, l = tid & 63, g4 = l >> 4, q16 = l & 15;
  f32x4 acc[4][4];
  #pragma unroll
  for (int mt = 0; mt < 4; ++mt)
    #pragma unroll
    for (int ct = 0; ct < 4; ++ct) acc[mt][ct] = f32x4{0.f, 0.f, 0.f, 0.f};
  #pragma unroll
  for (int kc = 0; kc < 8; ++kc){
    short8 a0[4], a1[4];
    #pragma unroll
    for (int mt = 0; mt < 4; ++mt){
      size_t off = ((size_t)(b * 8 + kc) * N2 + r0 + mt * 16 + q16) * 32 + g4 * 8;
      a0[mt] = *reinterpret_cast<const short8*>(A0 + off);
      a1[mt] = *reinterpret_cast<const short8*>(A1 + off);
    }
    #pragma unroll
    for (int ct = 0; ct < 4; ++ct){
      short8 bb = *reinterpret_cast<const short8*>(
          Wps + ((size_t)((w * 4 + ct) * 8 + kc) * 64 + l) * 8);   // coalesced 1KB
      #pragma unroll
      for (int mt = 0; mt < 4; ++mt){
        acc[mt][ct] = MFMA_BF16_K32(a0[mt], bb, acc[mt][ct]);
        acc[mt][ct] = MFMA_BF16_K32(a1[mt], bb, acc[mt][ct]);
      }
    }
  }
  #pragma unroll
  for (int mt = 0; mt < 4; ++mt){
    int orow[4];
    #pragma unroll
    for (int r = 0; r < 4; ++r) orow[r] = idx[b * Nn + r0 + mt * 16 + g4 * 4 + r];
    #pragma unroll
    for (int ct = 0; ct < 4; ++ct){
      int col = w * 64 + ct * 16 + q16;
      #pragma unroll
      for (int r = 0; r < 4; ++r)
        out[(size_t)(b * Nn + orow[r]) * DIMc + col] = acc[mt][ct][r];
    }
  }
}

extern "C" void kernel_launch(void* const* d_in, const int* in_sizes, int n_in,
                              void* d_out, int out_size, void* d_ws, size_t ws_size,
                              hipStream_t stream)
{
  const float* x   = (const float*)d_in[0];
  const int*   idx = (const int*)d_in[1];
  const float* kg  = (const float*)d_in[2];
  const float* vg  = (const float*)d_in[3];
  const float* Wq  = (const float*)d_in[4];
  const float* Wk  = (const float*)d_in[5];
  const float* Wv  = (const float*)d_in[6];
  const float* Wp  = (const float*)d_in[7];
  float* out = (float*)d_out;

  char* ws = (char*)d_ws;
  size_t off = 0;
  auto alloc = [&](size_t bytes) -> void* {
    void* p = ws + off; off += (bytes + 255) & ~(size_t)255; return p;
  };
  ushort_t* qh   = (ushort_t*)alloc((size_t)Bc * 8 * N2 * 16 * 2);
  ushort_t* kh   = (ushort_t*)alloc((size_t)Bc * 8 * N2 * 16 * 2);
  ushort_t* vT   = (ushort_t*)alloc((size_t)Bc * 256 * N2 * 2);
  ushort_t* aoh0 = (ushort_t*)alloc((size_t)Bc * 8 * N2 * 32 * 2);
  ushort_t* aoh1 = (ushort_t*)alloc((size_t)Bc * 8 * N2 * 32 * 2);
  ushort_t* Wcs  = (ushort_t*)alloc((size_t)512 * 256 * 2);
  ushort_t* Wps  = (ushort_t*)alloc((size_t)256 * 256 * 2);
  ushort_t* vgT  = (ushort_t*)alloc((size_t)8 * 32 * 256 * 2);
  ushort_t* kgb  = (ushort_t*)alloc((size_t)8 * 256 * 16 * 2);

  hipLaunchKernelGGL(prep_kernel,  dim3(1152), dim3(256), 0, stream,
                     Wq, Wk, Wv, Wp, kg, vg, Wcs, Wps, vgT, kgb);
  hipLaunchKernelGGL(proj_kernel,  dim3(250, 4), dim3(256), 0, stream, x, Wcs, idx, qh, kh, vT);
  hipLaunchKernelGGL(reflect_fill_kernel, dim3(864), dim3(256), 0, stream, qh, kh, vT);
  hipLaunchKernelGGL(attn_kernel,  dim3(63, 4, 4), dim3(256), 0, stream,
                     qh, kh, vT, kgb, vgT, aoh0, aoh1);
  hipLaunchKernelGGL(final_kernel, dim3(125, 4), dim3(256), 0, stream, aoh0, aoh1, Wps, idx, out);
}

// Round 28
// 95.600 us; speedup vs baseline: 1.0930x; 1.0930x over previous
//
#include <hip/hip_runtime.h>

typedef __attribute__((ext_vector_type(8))) short short8;
typedef __attribute__((ext_vector_type(4))) short short4v;
typedef __attribute__((ext_vector_type(4))) float f32x4;
typedef unsigned short ushort_t;

#define MFMA_BF16_K32(A,B,C) __builtin_amdgcn_mfma_f32_16x16x32_bf16(A,B,C,0,0,0)
#define MFMA_BF16_K16(A,B,C) __builtin_amdgcn_mfma_f32_16x16x16bf16_1k(A,B,C,0,0,0)

static constexpr int Bc  = 4;
static constexpr int Nn  = 8000;
static constexpr int N2  = 8192;
static constexpr int DIMc = 256;
static constexpr float SC2 = 0.36067376022224085f;   // 0.25 * log2(e), folded into Wq

__device__ __forceinline__ unsigned short f2bf(float f){
  unsigned int u = __float_as_uint(f);
  u = (u + 0x7FFFu + ((u >> 16) & 1u)) >> 16;
  return (unsigned short)u;
}
__device__ __forceinline__ uint2 pack4(f32x4 v){
  uint2 r;
  r.x = (unsigned)f2bf(v[0]) | ((unsigned)f2bf(v[1]) << 16);
  r.y = (unsigned)f2bf(v[2]) | ((unsigned)f2bf(v[3]) << 16);
  return r;
}
__device__ __forceinline__ unsigned cvtpk(float lo, float hi){
  unsigned r;
  asm("v_cvt_pk_bf16_f32 %0, %1, %2" : "=v"(r) : "v"(lo), "v"(hi));
  return r;
}
// raw v_exp_f32: args bounded (|x| < 40), no denorm fixup needed
__device__ __forceinline__ float rexp2(float x){
  float r;
  asm("v_exp_f32 %0, %1" : "=v"(r) : "v"(x));
  return r;
}
// permuted position of token t within its 32-block (V layout for dense PV loads)
__device__ __forceinline__ int vperm(int t){
  return (t & ~31) | (((t >> 2) & 3) * 8 + ((t >> 4) & 1) * 4 + (t & 3));
}

// ---- prep: Wcs/Wps fragment-major weights, vgT (token-permuted), kgb ----
__global__ __launch_bounds__(256) void prep_kernel(
    const float* __restrict__ Wq, const float* __restrict__ Wk,
    const float* __restrict__ Wv, const float* __restrict__ Wp,
    const float* __restrict__ kg, const float* __restrict__ vg,
    ushort_t* __restrict__ Wcs, ushort_t* __restrict__ Wps,
    ushort_t* __restrict__ vgT, ushort_t* __restrict__ kgb)
{
  int i = blockIdx.x * 256 + threadIdx.x;          // 294912 total
  if (i < 131072){
    int jj = i & 7, f = i >> 3;
    int l = f & 63, kc = (f >> 6) & 7, ctw = f >> 9;       // ctw 0..31
    int col = ctw * 16 + (l & 15);                          // 0..511
    int k   = kc * 32 + (l >> 4) * 8 + jj;
    float v;
    if (col < 128)      v = Wq[col * 256 + k] * SC2;
    else if (col < 256) v = Wk[(col - 128) * 256 + k];
    else                v = Wv[(col - 256) * 256 + k];
    Wcs[i] = f2bf(v);
  } else if (i < 196608){
    int o = i - 131072;                            // Wps, ctw 0..15
    int jj = o & 7, f = o >> 3;
    int l = f & 63, kc = (f >> 6) & 7, ctw = f >> 9;
    int col = ctw * 16 + (l & 15);
    int k   = kc * 32 + (l >> 4) * 8 + jj;
    Wps[o] = f2bf(Wp[col * 256 + k]);
  } else if (i < 262144){
    int o = i - 196608;                            // vg [8,256,32] -> vgT permuted
    int c = o & 31, m = (o >> 5) & 255, h = o >> 13;
    vgT[(h * 32 + c) * 256 + vperm(m)] = f2bf(vg[o]);
  } else {
    int j = i - 262144;
    kgb[j] = f2bf(kg[j]);
  }
}

// ---- QKV projection, M=64 per block; X staged via LDS; coalesced Wcs ----
__global__ __launch_bounds__(256) void proj_kernel(
    const float* __restrict__ X, const ushort_t* __restrict__ Wcs,
    const int* __restrict__ idx, ushort_t* __restrict__ qh,
    ushort_t* __restrict__ kh, ushort_t* __restrict__ vT)
{
  const int b  = blockIdx.y;
  const int r0 = blockIdx.x * 64;
  const int tid = threadIdx.x;
  const int w = tid >> 6, l = tid & 63, g4 = l >> 4, q16 = l & 15;
  __shared__ unsigned Xs[64][132];   // bf16x2 rows, pitch 132, 33.8 KB

  #pragma unroll
  for (int r = 0; r < 16; ++r){
    int row = r * 4 + w;
    int tok = idx[b * Nn + r0 + row];
    float4 xv = reinterpret_cast<const float4*>(X + (size_t)(b * Nn + tok) * DIMc)[l];
    uint2 u; u.x = cvtpk(xv.x, xv.y); u.y = cvtpk(xv.z, xv.w);
    *reinterpret_cast<uint2*>(&Xs[row][l * 2]) = u;
  }
  __syncthreads();

  f32x4 acc[4][8];
  #pragma unroll
  for (int mt = 0; mt < 4; ++mt)
    #pragma unroll
    for (int ct = 0; ct < 8; ++ct) acc[mt][ct] = f32x4{0.f, 0.f, 0.f, 0.f};
  #pragma unroll
  for (int kc = 0; kc < 8; ++kc){
    short8 a[4];
    #pragma unroll
    for (int mt = 0; mt < 4; ++mt){
      uint4 au = *reinterpret_cast<const uint4*>(&Xs[mt * 16 + q16][kc * 16 + g4 * 4]);
      a[mt] = __builtin_bit_cast(short8, au);
    }
    #pragma unroll
    for (int ct = 0; ct < 8; ++ct){
      short8 bb = *reinterpret_cast<const short8*>(
          Wcs + ((size_t)((w * 8 + ct) * 8 + kc) * 64 + l) * 8);   // coalesced 1KB
      #pragma unroll
      for (int mt = 0; mt < 4; ++mt) acc[mt][ct] = MFMA_BF16_K32(a[mt], bb, acc[mt][ct]);
    }
  }
  if (w < 2){
    ushort_t* dst = (w == 0) ? qh : kh;
    #pragma unroll
    for (int ct = 0; ct < 8; ++ct){
      #pragma unroll
      for (int mt = 0; mt < 4; ++mt){
        #pragma unroll
        for (int r = 0; r < 4; ++r){
          int j = r0 + mt * 16 + g4 * 4 + r;
          dst[((size_t)(b * 8 + ct) * N2 + j) * 16 + q16] = f2bf(acc[mt][ct][r]);
        }
      }
    }
  } else {
    #pragma unroll
    for (int ct = 0; ct < 8; ++ct){
      int col = (w - 2) * 128 + ct * 16 + q16;
      #pragma unroll
      for (int mt = 0; mt < 4; ++mt){
        int jb = r0 + (mt >> 1) * 32 + g4 * 8 + (mt & 1) * 4;
        *reinterpret_cast<uint2*>(vT + (size_t)(b * 256 + col) * N2 + jb) = pack4(acc[mt][ct]);
      }
    }
  }
}

// ---- reflected tails ----
__global__ __launch_bounds__(256) void reflect_fill_kernel(
    ushort_t* __restrict__ qh, ushort_t* __restrict__ kh, ushort_t* __restrict__ vT)
{
  int t = blockIdx.x * 256 + threadIdx.x;
  if (t < 24576){
    int e = t & 1;
    int r = (t >> 1) % 192;
    int p = (t >> 1) / 192;
    int b = p >> 4, q = p & 15;
    ushort_t* base = (q < 8) ? qh : kh;
    int h = q & 7;
    size_t plane = (size_t)(b * 8 + h) * N2 * 16;
    const uint4* src = reinterpret_cast<const uint4*>(base + plane + (size_t)(7999 - r) * 16);
    uint4*       dst = reinterpret_cast<uint4*>(base + plane + (size_t)(8000 + r) * 16);
    dst[e] = src[e];
  } else {
    int u = t - 24576;
    int r = u / 192, i2 = u % 192;
    vT[(size_t)r * N2 + vperm(8000 + i2)] = vT[(size_t)r * N2 + vperm(7999 - i2)];
  }
}

// ---- fused attention: wave = (head, pass), fully independent (no LDS/barrier).
// grid (63, 4, 4); 4 waves = 2 heads x {local, global}; partial buffers
// summed inside final's K=512 GEMM. ----
__global__ __launch_bounds__(256) void attn_kernel(
    const ushort_t* __restrict__ qh, const ushort_t* __restrict__ kh,
    const ushort_t* __restrict__ vT,
    const ushort_t* __restrict__ kg, const ushort_t* __restrict__ vgT,
    ushort_t* __restrict__ aoh0, ushort_t* __restrict__ aoh1)
{
  const int go = blockIdx.x, hp = blockIdx.y, b = blockIdx.z;
  const int tid = threadIdx.x;
  const int w = tid >> 6, l = tid & 63, g4 = l >> 4, q16 = l & 15;
  const int h = hp * 2 + (w >> 1);
  const int pass = w & 1;                    // 0 = local window, 1 = global
  const f32x4 z4 = {0.f, 0.f, 0.f, 0.f};
  const size_t bh = (size_t)(b * 8 + h);
  const ushort_t* Qb = qh + (bh * N2 + go * 128) * 16;
  ushort_t*       Ob = (pass ? aoh1 : aoh0) + (bh * N2 + go * 128) * 32;

  short8 ones;
  #pragma unroll
  for (int j = 0; j < 8; ++j) ones[j] = (short)0x3F80;   // bf16 1.0

  const ushort_t* kbase = pass ? (kg + (size_t)h * 256 * 16)
                               : (kh + (bh * N2 + go * 128) * 16);
  short4v karr[16];
  #pragma unroll
  for (int t = 0; t < 16; ++t)
    karr[t] = *reinterpret_cast<const short4v*>(
        kbase + (size_t)(t * 16 + q16) * 16 + g4 * 4);
  const ushort_t* v0;
  size_t rstride;
  if (!pass){
    v0 = vT + (size_t)(b * 256 + h * 32) * N2 + go * 128 + (size_t)q16 * N2 + g4 * 8;
    rstride = (size_t)16 * N2;
  } else {
    v0 = vgT + (size_t)h * 32 * 256 + (size_t)q16 * 256 + g4 * 8;
    rstride = (size_t)16 * 256;
  }
  uint4 va[8], vb[8];
  #pragma unroll
  for (int t2 = 0; t2 < 8; ++t2){
    va[t2] = *reinterpret_cast<const uint4*>(v0 + t2 * 32);
    vb[t2] = *reinterpret_cast<const uint4*>(v0 + rstride + t2 * 32);
  }

  #pragma unroll 2
  for (int qt = 0; qt < 8; ++qt){
    short4v qf = *reinterpret_cast<const short4v*>(
        Qb + (size_t)(qt * 16 + q16) * 16 + g4 * 4);
    // ---- S^T = K @ Q^T (scale pre-folded into q) ----
    f32x4 s[16];
    __builtin_amdgcn_s_setprio(1);
    #pragma unroll
    for (int t = 0; t < 16; ++t) s[t] = MFMA_BF16_K16(karr[t], qf, z4);
    __builtin_amdgcn_s_setprio(0);
    // ---- P = exp2(S) packed bf16 ----
    uint4 p4[8];
    #pragma unroll
    for (int t2 = 0; t2 < 8; ++t2){
      float e0 = rexp2(s[2*t2][0]);
      float e1 = rexp2(s[2*t2][1]);
      float e2 = rexp2(s[2*t2][2]);
      float e3 = rexp2(s[2*t2][3]);
      float f0 = rexp2(s[2*t2+1][0]);
      float f1 = rexp2(s[2*t2+1][1]);
      float f2 = rexp2(s[2*t2+1][2]);
      float f3 = rexp2(s[2*t2+1][3]);
      p4[t2].x = cvtpk(e0, e1); p4[t2].y = cvtpk(e2, e3);
      p4[t2].z = cvtpk(f0, f1); p4[t2].w = cvtpk(f2, f3);
    }
    // ---- O^T = V^T @ P ; denominator via ones-MFMA (no shfl) ----
    f32x4 o0 = z4, o1 = z4, dacc = z4;
    __builtin_amdgcn_s_setprio(1);
    #pragma unroll
    for (int t2 = 0; t2 < 8; ++t2){
      short8 pf = __builtin_bit_cast(short8, p4[t2]);
      o0   = MFMA_BF16_K32(__builtin_bit_cast(short8, va[t2]), pf, o0);
      o1   = MFMA_BF16_K32(__builtin_bit_cast(short8, vb[t2]), pf, o1);
      dacc = MFMA_BF16_K32(ones, pf, dacc);
    }
    __builtin_amdgcn_s_setprio(0);
    float invd = 1.0f / dacc[0];
    uint2 s0, s1;
    s0.x = cvtpk(o0[0] * invd, o0[1] * invd);
    s0.y = cvtpk(o0[2] * invd, o0[3] * invd);
    s1.x = cvtpk(o1[0] * invd, o1[1] * invd);
    s1.y = cvtpk(o1[2] * invd, o1[3] * invd);
    size_t base = (size_t)(qt * 16 + q16) * 32;
    *reinterpret_cast<uint2*>(Ob + base + g4 * 4)      = s0;
    *reinterpret_cast<uint2*>(Ob + base + 16 + g4 * 4) = s1;
  }
}

// ---- final: out[idx[b,j]] = (A0[b,j] + A1[b,j]) @ Wp^T via K=512 GEMM ----
__global__ __launch_bounds__(256) void final_kernel(
    const ushort_t* __restrict__ A0, const ushort_t* __restrict__ A1,
    const ushort_t* __restrict__ Wps,
    const int* __restrict__ idx, float* __restrict__ out)
{
  const int b  = blockIdx.y;
  const int r0 = blockIdx.x * 64;
  const int tid = threadIdx.x;
  const int w = tid >> 6, l = tid & 63, g4 = l >> 4, q16 = l & 15;
  f32x4 acc[4][4];
  #pragma unroll
  for (int mt = 0; mt < 4; ++mt)
    #pragma unroll
    for (int ct = 0; ct < 4; ++ct) acc[mt][ct] = f32x4{0.f, 0.f, 0.f, 0.f};
  #pragma unroll
  for (int kc = 0; kc < 8; ++kc){
    short8 a0[4], a1[4];
    #pragma unroll
    for (int mt = 0; mt < 4; ++mt){
      size_t off = ((size_t)(b * 8 + kc) * N2 + r0 + mt * 16 + q16) * 32 + g4 * 8;
      a0[mt] = *reinterpret_cast<const short8*>(A0 + off);
      a1[mt] = *reinterpret_cast<const short8*>(A1 + off);
    }
    #pragma unroll
    for (int ct = 0; ct < 4; ++ct){
      short8 bb = *reinterpret_cast<const short8*>(
          Wps + ((size_t)((w * 4 + ct) * 8 + kc) * 64 + l) * 8);   // coalesced 1KB
      #pragma unroll
      for (int mt = 0; mt < 4; ++mt){
        acc[mt][ct] = MFMA_BF16_K32(a0[mt], bb, acc[mt][ct]);
        acc[mt][ct] = MFMA_BF16_K32(a1[mt], bb, acc[mt][ct]);
      }
    }
  }
  #pragma unroll
  for (int mt = 0; mt < 4; ++mt){
    int orow[4];
    #pragma unroll
    for (int r = 0; r < 4; ++r) orow[r] = idx[b * Nn + r0 + mt * 16 + g4 * 4 + r];
    #pragma unroll
    for (int ct = 0; ct < 4; ++ct){
      int col = w * 64 + ct * 16 + q16;
      #pragma unroll
      for (int r = 0; r < 4; ++r)
        out[(size_t)(b * Nn + orow[r]) * DIMc + col] = acc[mt][ct][r];
    }
  }
}

extern "C" void kernel_launch(void* const* d_in, const int* in_sizes, int n_in,
                              void* d_out, int out_size, void* d_ws, size_t ws_size,
                              hipStream_t stream)
{
  const float* x   = (const float*)d_in[0];
  const int*   idx = (const int*)d_in[1];
  const float* kg  = (const float*)d_in[2];
  const float* vg  = (const float*)d_in[3];
  const float* Wq  = (const float*)d_in[4];
  const float* Wk  = (const float*)d_in[5];
  const float* Wv  = (const float*)d_in[6];
  const float* Wp  = (const float*)d_in[7];
  float* out = (float*)d_out;

  char* ws = (char*)d_ws;
  size_t off = 0;
  auto alloc = [&](size_t bytes) -> void* {
    void* p = ws + off; off += (bytes + 255) & ~(size_t)255; return p;
  };
  ushort_t* qh   = (ushort_t*)alloc((size_t)Bc * 8 * N2 * 16 * 2);
  ushort_t* kh   = (ushort_t*)alloc((size_t)Bc * 8 * N2 * 16 * 2);
  ushort_t* vT   = (ushort_t*)alloc((size_t)Bc * 256 * N2 * 2);
  ushort_t* aoh0 = (ushort_t*)alloc((size_t)Bc * 8 * N2 * 32 * 2);
  ushort_t* aoh1 = (ushort_t*)alloc((size_t)Bc * 8 * N2 * 32 * 2);
  ushort_t* Wcs  = (ushort_t*)alloc((size_t)512 * 256 * 2);
  ushort_t* Wps  = (ushort_t*)alloc((size_t)256 * 256 * 2);
  ushort_t* vgT  = (ushort_t*)alloc((size_t)8 * 32 * 256 * 2);
  ushort_t* kgb  = (ushort_t*)alloc((size_t)8 * 256 * 16 * 2);

  hipLaunchKernelGGL(prep_kernel,  dim3(1152), dim3(256), 0, stream,
                     Wq, Wk, Wv, Wp, kg, vg, Wcs, Wps, vgT, kgb);
  hipLaunchKernelGGL(proj_kernel,  dim3(125, 4), dim3(256), 0, stream, x, Wcs, idx, qh, kh, vT);
  hipLaunchKernelGGL(reflect_fill_kernel, dim3(864), dim3(256), 0, stream, qh, kh, vT);
  hipLaunchKernelGGL(attn_kernel,  dim3(63, 4, 4), dim3(256), 0, stream,
                     qh, kh, vT, kgb, vgT, aoh0, aoh1);
  hipLaunchKernelGGL(final_kernel, dim3(125, 4), dim3(256), 0, stream, aoh0, aoh1, Wps, idx, out);
}